// Round 1
// baseline (180.757 us; speedup 1.0000x reference)
//
#include <hip/hip_runtime.h>
#include <stdint.h>

#define B_DIM 4096
#define C_DIM 32
#define D_DIM 128
#define R_DIM 8
#define BM    64
#define NTHREADS 256

typedef __bf16 bf16x8 __attribute__((ext_vector_type(8)));
typedef float  f32x4  __attribute__((ext_vector_type(4)));

// f32 -> bf16 bits, round-to-nearest-even
__device__ __forceinline__ uint32_t f2bf(float f) {
  uint32_t u = __float_as_uint(f);
  return (u + 0x7FFFu + ((u >> 16) & 1u)) >> 16;
}

// XOR swizzle: row-major [row][256B], flip byte bits 4-6 by row&7.
// Breaks the 32-way bank conflict of stride-256B column reads (ds_read_b128).
__device__ __forceinline__ uint32_t swz(uint32_t row, uint32_t colbyte) {
  return row * 256u + (colbyte ^ ((row & 7u) << 4));
}

__global__ __launch_bounds__(NTHREADS, 3)
void rot_kernel(const float* __restrict__ src, const float* __restrict__ data,
                const float* __restrict__ W, const float* __restrict__ Aa,
                const float* __restrict__ Cc, const float* __restrict__ Dd,
                float* __restrict__ out)
{
  __shared__ __align__(16) unsigned char ldsS[BM  * 256];   // 16 KB bf16 source tile
  __shared__ __align__(16) unsigned char ldsW[128 * 256];   // 32 KB bf16 W_r tile

  const uint32_t tid  = threadIdx.x;
  const uint32_t lane = tid & 63u;
  const uint32_t wid  = tid >> 6;     // wave id 0..3, owns rows [wid*16, wid*16+16)
  const uint32_t l15  = lane & 15u;
  const uint32_t lg   = lane >> 4;    // quarter-wave group 0..3

  const uint32_t c0     = blockIdx.x & 31u;          // fixed C index for this block
  const uint32_t b_base = (blockIdx.x >> 5) * BM;    // 64 consecutive b values

  // ---- stage source tile: f32 -> bf16 (RTNE), swizzled LDS [m][k] ----
  #pragma unroll
  for (int it = 0; it < 8; ++it) {
    uint32_t flat = (uint32_t)it * 1024u + tid * 4u;   // 8192 floats
    uint32_t m = flat >> 7, i = flat & 127u;
    const float4 s4 = *reinterpret_cast<const float4*>(
        src + ((size_t)(b_base + m) * C_DIM + c0) * D_DIM + i);
    uint2 p;
    p.x = f2bf(s4.x) | (f2bf(s4.y) << 16);
    p.y = f2bf(s4.z) | (f2bf(s4.w) << 16);
    *reinterpret_cast<uint2*>(&ldsS[swz(m, i * 2u)]) = p;
  }

  // ---- x (data) in registers, laid out exactly like MFMA C/D fragments ----
  // element (n,q) of thread = row (wid*16 + lg*4 + q), col (n*16 + l15)
  float x[8][4];
  #pragma unroll
  for (int q = 0; q < 4; ++q) {
    const float* xr = data + ((size_t)(b_base + wid * 16 + lg * 4 + q) * C_DIM + c0) * D_DIM;
    #pragma unroll
    for (int n = 0; n < 8; ++n) x[n][q] = xr[n * 16 + l15];
  }

  for (int r = 0; r < R_DIM; ++r) {
    __syncthreads();   // all waves done reading previous W_r (and, on r=0, covers ldsS writes)

    // ---- stage W_r: f32 -> bf16, swizzled LDS [o][k] (W is [R][Dout][Din] row-major) ----
    const float* Wr = W + (size_t)r * (D_DIM * D_DIM);
    #pragma unroll
    for (int it = 0; it < 16; ++it) {
      uint32_t flat = (uint32_t)it * 1024u + tid * 4u;  // 16384 floats
      uint32_t o = flat >> 7, i = flat & 127u;
      const float4 w4 = *reinterpret_cast<const float4*>(Wr + flat);
      uint2 p;
      p.x = f2bf(w4.x) | (f2bf(w4.y) << 16);
      p.y = f2bf(w4.z) | (f2bf(w4.w) << 16);
      *reinterpret_cast<uint2*>(&ldsW[swz(o, i * 2u)]) = p;
    }

    // a/c/d depend only on (r, c0, col) -> 8 values each per lane, L1 broadcast
    float av[8], cv[8], dv[8];
    const size_t acd_base = ((size_t)r * C_DIM + c0) * D_DIM;
    #pragma unroll
    for (int n = 0; n < 8; ++n) {
      av[n] = Aa[acd_base + n * 16 + l15];
      cv[n] = Cc[acd_base + n * 16 + l15];
      dv[n] = Dd[acd_base + n * 16 + l15];
    }
    __syncthreads();

    // ---- V = S @ W_r^T via mfma_f32_16x16x32_bf16 ----
    f32x4 acc[8];
    #pragma unroll
    for (int n = 0; n < 8; ++n) acc[n] = (f32x4){0.f, 0.f, 0.f, 0.f};
    #pragma unroll
    for (int kt = 0; kt < 4; ++kt) {
      const uint32_t kb = (uint32_t)kt * 64u + lg * 16u;  // byte offset of k in row
      bf16x8 af = *reinterpret_cast<const bf16x8*>(&ldsS[swz(wid * 16 + l15, kb)]);
      #pragma unroll
      for (int n = 0; n < 8; ++n) {
        bf16x8 bq = *reinterpret_cast<const bf16x8*>(&ldsW[swz(n * 16 + l15, kb)]);
        acc[n] = __builtin_amdgcn_mfma_f32_16x16x32_bf16(af, bq, acc[n], 0, 0, 0);
      }
    }

    // ---- epilogue: t = tanh(a*v)*c + d; u = t/max(||t||,eps); x -= 2 u (u.x) ----
    float s2[4] = {0.f, 0.f, 0.f, 0.f};
    #pragma unroll
    for (int n = 0; n < 8; ++n) {
      #pragma unroll
      for (int q = 0; q < 4; ++q) {
        float t = tanhf(av[n] * acc[n][q]) * cv[n] + dv[n];
        acc[n][q] = t;
        s2[q] += t * t;
      }
    }
    // row = (lg, q); sum across the 16 lanes (l15) of each quarter-group
    #pragma unroll
    for (int m = 1; m <= 8; m <<= 1) {
      #pragma unroll
      for (int q = 0; q < 4; ++q) s2[q] += __shfl_xor(s2[q], m);
    }
    float inv[4], dt[4] = {0.f, 0.f, 0.f, 0.f};
    #pragma unroll
    for (int q = 0; q < 4; ++q) inv[q] = 1.f / fmaxf(sqrtf(s2[q]), 1e-12f);
    #pragma unroll
    for (int n = 0; n < 8; ++n) {
      #pragma unroll
      for (int q = 0; q < 4; ++q) {
        float u = acc[n][q] * inv[q];
        acc[n][q] = u;
        dt[q] += u * x[n][q];
      }
    }
    #pragma unroll
    for (int m = 1; m <= 8; m <<= 1) {
      #pragma unroll
      for (int q = 0; q < 4; ++q) dt[q] += __shfl_xor(dt[q], m);
    }
    #pragma unroll
    for (int n = 0; n < 8; ++n) {
      #pragma unroll
      for (int q = 0; q < 4; ++q)
        x[n][q] = fmaf(-2.f * dt[q], acc[n][q], x[n][q]);
    }
  }

  // ---- store ----
  #pragma unroll
  for (int q = 0; q < 4; ++q) {
    float* orow = out + ((size_t)(b_base + wid * 16 + lg * 4 + q) * C_DIM + c0) * D_DIM;
    #pragma unroll
    for (int n = 0; n < 8; ++n) orow[n * 16 + l15] = x[n][q];
  }
}

extern "C" void kernel_launch(void* const* d_in, const int* in_sizes, int n_in,
                              void* d_out, int out_size, void* d_ws, size_t ws_size,
                              hipStream_t stream) {
  const float* src  = (const float*)d_in[0];
  const float* data = (const float*)d_in[1];
  const float* W    = (const float*)d_in[2];
  const float* Aa   = (const float*)d_in[3];
  const float* Cc   = (const float*)d_in[4];
  const float* Dd   = (const float*)d_in[5];
  float* out = (float*)d_out;

  dim3 grid((B_DIM / BM) * C_DIM);   // 2048 workgroups
  dim3 block(NTHREADS);
  rot_kernel<<<grid, block, 0, stream>>>(src, data, W, Aa, Cc, Dd, out);
}

// Round 2
// 105.287 us; speedup vs baseline: 1.7168x; 1.7168x over previous
//
#include <hip/hip_runtime.h>
#include <stdint.h>

#define B_DIM 4096
#define C_DIM 32
#define D_DIM 128
#define R_DIM 8
#define BM    64
#define NTHREADS 256

typedef __bf16 bf16x8 __attribute__((ext_vector_type(8)));
typedef float  f32x4  __attribute__((ext_vector_type(4)));

// f32 -> bf16 bits, round-to-nearest-even
__device__ __forceinline__ uint32_t f2bf(float f) {
  uint32_t u = __float_as_uint(f);
  return (u + 0x7FFFu + ((u >> 16) & 1u)) >> 16;
}

// XOR swizzle: row-major [row][256B], flip byte bits 4-6 by row&7.
// Breaks the 32-way bank conflict of stride-256B column reads (ds_read_b128).
__device__ __forceinline__ uint32_t swz(uint32_t row, uint32_t colbyte) {
  return row * 256u + (colbyte ^ ((row & 7u) << 4));
}

#if __has_builtin(__builtin_amdgcn_exp2f)
#define EXP2F(x) __builtin_amdgcn_exp2f(x)
#else
#define EXP2F(x) exp2f(x)
#endif
#if __has_builtin(__builtin_amdgcn_rcpf)
#define RCPF(x) __builtin_amdgcn_rcpf(x)
#else
#define RCPF(x) (1.0f / (x))
#endif

// 16B async global->LDS. LDS dest = wave-uniform base + lane*16; global addr per-lane.
__device__ __forceinline__ void load_lds16(const void* g, void* l) {
  __builtin_amdgcn_global_load_lds(
      (const __attribute__((address_space(1))) uint32_t*)g,
      (__attribute__((address_space(3))) uint32_t*)l, 16, 0, 0);
}

// ---- prep: W f32 -> bf16, PRE-PERMUTED so a linear LDS copy lands swizzled ----
// ws byte L (within [r][128 rows][256B]) holds bf16 of W[r][o][colbyte/2],
// where o=(L>>8)&127, rb=L&255, colbyte = rb ^ ((o&7)<<4).
__global__ void prep_w(const float* __restrict__ W, uint32_t* __restrict__ ws) {
  uint32_t t = blockIdx.x * 256u + threadIdx.x;       // 65536 threads, 4B each
  uint32_t L = t * 4u;
  uint32_t o  = (L >> 8) & 127u;
  uint32_t rb = L & 255u;
  uint32_t colbyte = rb ^ ((o & 7u) << 4);            // flips bits 4-6 only; 4B pairs intact
  uint32_t eidx = (L >> 15) * 16384u + o * 128u + (colbyte >> 1);
  float2 w2 = *reinterpret_cast<const float2*>(W + eidx);
  ws[t] = f2bf(w2.x) | (f2bf(w2.y) << 16);
}

__global__ __launch_bounds__(NTHREADS, 3)
void rot_kernel(const float* __restrict__ src, const float* __restrict__ data,
                const uint8_t* __restrict__ wsw, const float* __restrict__ Aa,
                const float* __restrict__ Cc, const float* __restrict__ Dd,
                float* __restrict__ out)
{
  __shared__ __align__(16) unsigned char ldsS[BM  * 256];   // 16 KB bf16 source tile
  __shared__ __align__(16) unsigned char ldsW[128 * 256];   // 32 KB bf16 W_r tile

  const uint32_t tid  = threadIdx.x;
  const uint32_t lane = tid & 63u;
  const uint32_t wid  = tid >> 6;     // wave id 0..3, owns rows [wid*16, wid*16+16)
  const uint32_t l15  = lane & 15u;
  const uint32_t lg   = lane >> 4;    // quarter-wave group 0..3

  const uint32_t c0     = blockIdx.x & 31u;          // fixed C index for this block
  const uint32_t b_base = (blockIdx.x >> 5) * BM;    // 64 consecutive b values

  // ---- stage source tile: f32 -> bf16 (RTNE), swizzled LDS [m][k] ----
  #pragma unroll
  for (int it = 0; it < 8; ++it) {
    uint32_t flat = (uint32_t)it * 1024u + tid * 4u;   // 8192 floats
    uint32_t m = flat >> 7, i = flat & 127u;
    const float4 s4 = *reinterpret_cast<const float4*>(
        src + ((size_t)(b_base + m) * C_DIM + c0) * D_DIM + i);
    uint2 p;
    p.x = f2bf(s4.x) | (f2bf(s4.y) << 16);
    p.y = f2bf(s4.z) | (f2bf(s4.w) << 16);
    *reinterpret_cast<uint2*>(&ldsS[swz(m, i * 2u)]) = p;
  }

  // ---- x (data) in registers, laid out exactly like MFMA C/D fragments ----
  // element (n,q) of thread = row (wid*16 + lg*4 + q), col (n*16 + l15)
  float x[8][4];
  #pragma unroll
  for (int q = 0; q < 4; ++q) {
    const float* xr = data + ((size_t)(b_base + wid * 16 + lg * 4 + q) * C_DIM + c0) * D_DIM;
    #pragma unroll
    for (int n = 0; n < 8; ++n) x[n][q] = xr[n * 16 + l15];
  }

  for (int r = 0; r < R_DIM; ++r) {
    __syncthreads();   // all waves done reading previous W_r (and, on r=0, covers ldsS writes)

    // ---- stage W_r: pre-permuted bf16 in ws -> linear global_load_lds (zero VALU) ----
    {
      const uint8_t* g = wsw + (uint32_t)r * 32768u + wid * 1024u + lane * 16u;
      #pragma unroll
      for (int j = 0; j < 8; ++j)
        load_lds16(g + j * 4096u, &ldsW[wid * 1024u + (uint32_t)j * 4096u]);
    }

    // a/c/d depend only on (r, c0, col): fold constants while loads are in flight
    float a2[8], m2c[8], cdv[8];
    const size_t acd_base = ((size_t)r * C_DIM + c0) * D_DIM;
    #pragma unroll
    for (int n = 0; n < 8; ++n) {
      float av = Aa[acd_base + n * 16 + l15];
      float cv = Cc[acd_base + n * 16 + l15];
      float dv = Dd[acd_base + n * 16 + l15];
      a2[n]  = av * 2.88539008177793f;   // 2*log2(e), folds tanh's 2z and exp2 conversion
      m2c[n] = -2.f * cv;
      cdv[n] = cv + dv;
    }
    __syncthreads();   // drains vmcnt(0) -> W_r fully in LDS

    // ---- V = S @ W_r^T via mfma_f32_16x16x32_bf16 ----
    f32x4 acc[8];
    #pragma unroll
    for (int n = 0; n < 8; ++n) acc[n] = (f32x4){0.f, 0.f, 0.f, 0.f};
    #pragma unroll
    for (int kt = 0; kt < 4; ++kt) {
      const uint32_t kb = (uint32_t)kt * 64u + lg * 16u;  // byte offset of k in row
      bf16x8 af = *reinterpret_cast<const bf16x8*>(&ldsS[swz(wid * 16 + l15, kb)]);
      #pragma unroll
      for (int n = 0; n < 8; ++n) {
        bf16x8 bq = *reinterpret_cast<const bf16x8*>(&ldsW[swz(n * 16 + l15, kb)]);
        acc[n] = __builtin_amdgcn_mfma_f32_16x16x32_bf16(af, bq, acc[n], 0, 0, 0);
      }
    }

    // ---- epilogue: t = tanh(a*v)*c + d;  x -= 2*t*(t.x)/max(||t||,eps)^2 ----
    // tanh(z) = 1 - 2/(exp2(z*2log2e)+1); c,d folded: t = fma(-2c, p, c+d)
    float s2[4] = {0.f, 0.f, 0.f, 0.f}, tx[4] = {0.f, 0.f, 0.f, 0.f};
    #pragma unroll
    for (int n = 0; n < 8; ++n) {
      #pragma unroll
      for (int q = 0; q < 4; ++q) {
        float e = EXP2F(a2[n] * acc[n][q]);
        float t = fmaf(m2c[n], RCPF(e + 1.f), cdv[n]);
        acc[n][q] = t;
        s2[q] = fmaf(t, t, s2[q]);
        tx[q] = fmaf(t, x[n][q], tx[q]);
      }
    }
    // single combined reduction tree across the 16 lanes of each quarter-group
    #pragma unroll
    for (int m = 1; m <= 8; m <<= 1) {
      #pragma unroll
      for (int q = 0; q < 4; ++q) {
        s2[q] += __shfl_xor(s2[q], m);
        tx[q] += __shfl_xor(tx[q], m);
      }
    }
    float scale[4];
    #pragma unroll
    for (int q = 0; q < 4; ++q)
      scale[q] = -2.f * tx[q] * RCPF(fmaxf(s2[q], 1e-24f));  // == -2*dot/max(||t||,eps)^2
    #pragma unroll
    for (int n = 0; n < 8; ++n) {
      #pragma unroll
      for (int q = 0; q < 4; ++q)
        x[n][q] = fmaf(scale[q], acc[n][q], x[n][q]);
    }
  }

  // ---- store ----
  #pragma unroll
  for (int q = 0; q < 4; ++q) {
    float* orow = out + ((size_t)(b_base + wid * 16 + lg * 4 + q) * C_DIM + c0) * D_DIM;
    #pragma unroll
    for (int n = 0; n < 8; ++n) orow[n * 16 + l15] = x[n][q];
  }
}

extern "C" void kernel_launch(void* const* d_in, const int* in_sizes, int n_in,
                              void* d_out, int out_size, void* d_ws, size_t ws_size,
                              hipStream_t stream) {
  const float* src  = (const float*)d_in[0];
  const float* data = (const float*)d_in[1];
  const float* W    = (const float*)d_in[2];
  const float* Aa   = (const float*)d_in[3];
  const float* Cc   = (const float*)d_in[4];
  const float* Dd   = (const float*)d_in[5];
  float* out = (float*)d_out;

  // prep: 8*128*128 f32 -> 256 KB pre-permuted bf16 in workspace
  prep_w<<<dim3(256), dim3(256), 0, stream>>>(W, (uint32_t*)d_ws);

  dim3 grid((B_DIM / BM) * C_DIM);   // 2048 workgroups
  dim3 block(NTHREADS);
  rot_kernel<<<grid, block, 0, stream>>>(src, data, (const uint8_t*)d_ws,
                                         Aa, Cc, Dd, out);
}